// Round 12
// baseline (366.819 us; speedup 1.0000x reference)
//
#include <hip/hip_runtime.h>
#include <stdint.h>

// ---------------------------------------------------------------------------
// Sizes (fixed by the reference)
// ---------------------------------------------------------------------------
#define BB 8192
#define NN 64
#define CC 8
#define DD 512   // N*C
#define HPP 1024
#define HSS 512

typedef _Float16 f16x8 __attribute__((ext_vector_type(8)));
typedef float f32x4 __attribute__((ext_vector_type(4)));

// ---------------------------------------------------------------------------
// JAX threefry2x32 (exact) — partitionable variant (verified round 5)
// ---------------------------------------------------------------------------
__host__ __device__ __forceinline__ void threefry2x32(
    uint32_t k0, uint32_t k1, uint32_t x0, uint32_t x1,
    uint32_t& o0, uint32_t& o1)
{
  const uint32_t ks2 = k0 ^ k1 ^ 0x1BD11BDAu;
#define TFR(r) { x0 += x1; x1 = (x1 << (r)) | (x1 >> (32 - (r))); x1 ^= x0; }
  x0 += k0; x1 += k1;
  TFR(13) TFR(15) TFR(26) TFR(6)
  x0 += k1;  x1 += ks2 + 1u;
  TFR(17) TFR(29) TFR(16) TFR(24)
  x0 += ks2; x1 += k0 + 2u;
  TFR(13) TFR(15) TFR(26) TFR(6)
  x0 += k0;  x1 += k1 + 3u;
  TFR(17) TFR(29) TFR(16) TFR(24)
  x0 += k1;  x1 += ks2 + 4u;
  TFR(13) TFR(15) TFR(26) TFR(6)
  x0 += ks2; x1 += k0 + 5u;
#undef TFR
  o0 = x0; o1 = x1;
}

__device__ __forceinline__ uint32_t tf_bits_p(uint32_t k0, uint32_t k1,
                                              uint32_t idx)
{
  uint32_t o0, o1;
  threefry2x32(k0, k1, 0u, idx, o0, o1);
  return o0 ^ o1;
}

__device__ __forceinline__ float jax_uniform(uint32_t bits)
{
  const float f = __uint_as_float((bits >> 9) | 0x3f800000u) - 1.0f;
  return fmaxf(1e-8f, f + 1e-8f);
}

// ---------------------------------------------------------------------------
// Swizzled split-fp16 plane layout (validated round 8: bank conflicts = 0).
//   kswz(k, r) = chunk(k) | ((((k>>3) ^ (r>>1)) & 3) << 3) | (k & 7)
// ---------------------------------------------------------------------------
__device__ __forceinline__ int kswz(int k, int r)
{
  return (k & ~31) | ((((k >> 3) ^ (r >> 1)) & 3) << 3) | (k & 7);
}

// async 16B global -> LDS copy (direct-to-LDS DMA)
__device__ __forceinline__ void async_copy16(void* lds, const void* g)
{
  __builtin_amdgcn_global_load_lds(
      (const __attribute__((address_space(1))) unsigned int*)g,
      (__attribute__((address_space(3))) unsigned int*)lds,
      16, 0, 0);
}

// stage a ROWSx32 fp16 tile (pre-swizzled global) into LDS, linear copy
template<int ROWS>
__device__ __forceinline__ void stage_tile(_Float16* lds, const _Float16* g,
                                           int row0, int ldK, int k0, int tid)
{
  constexpr int SLOTS = ROWS * 4;  // 16B slots
#pragma unroll
  for (int s0 = 0; s0 < SLOTS; s0 += 256) {
    const int s = s0 + tid;
    const char* gp = (const char*)(g + (size_t)(row0 + (s >> 2)) * ldK + k0)
                     + (s & 3) * 16;
    async_copy16((char*)lds + (size_t)s * 16, gp);
  }
}

// read one 16x32 MFMA fragment row-slice from a swizzled LDS plane
__device__ __forceinline__ f16x8 frag_ld(const _Float16* base, int row, int lk)
{
  const int off = row * 32 + (((lk ^ (row >> 1)) & 3) << 3);
  return *(const f16x8*)(base + off);
}

// ---------------------------------------------------------------------------
// Split-fp16 MFMA GEMM.  C[M,N] = act(A[M,K] @ B[K,N] + bias)
// Round-10 change: BN=64 for all big GEMMs (grid 2x -> 4 blocks/CU; the
// round-9 counters showed Occupancy 19% / MfmaUtil 38% with nothing
// saturated -> barrier-drain stall not hidden at 2 blocks/CU).
// EPI: 0 = relu+split planes; 1 = f32 sigmoid; 2 = f32 none;
//      3 = dual relu+split (cols<512 -> C1/N=512/bias1, else C2/N=1024/bias2)
// ---------------------------------------------------------------------------
template<int BM, int BN, int ALO, int EPI>
__global__ __launch_bounds__(256, 4)
void gemm_mfma(const _Float16* __restrict__ Ahi, const _Float16* __restrict__ Alo,
               const _Float16* __restrict__ BhiT, const _Float16* __restrict__ BloT,
               const float* __restrict__ bias,
               _Float16* __restrict__ ChiOut, _Float16* __restrict__ CloOut,
               float* __restrict__ Cf32,
               int M, int N, int K,
               const float* __restrict__ bias2,
               _Float16* __restrict__ Chi2, _Float16* __restrict__ Clo2)
{
  __shared__ __align__(16) _Float16 As_hi[BM * 32];
  __shared__ __align__(16) _Float16 As_lo[ALO ? BM * 32 : 8];
  __shared__ __align__(16) _Float16 Bs_hi[BN * 32];
  __shared__ __align__(16) _Float16 Bs_lo[BN * 32];

  const int tid = threadIdx.x;
  const int wid = tid >> 6, lane = tid & 63;
  const int wr = wid >> 1, wc = wid & 1;
  constexpr int WROWS = BM / 2, WCOLS = BN / 2;
  constexpr int FRM = WROWS / 16, FRN = WCOLS / 16;
  const int lr = lane & 15, lk = lane >> 4;

  // T1 XCD-aware chunked swizzle (validated round 9: FETCH 133->33MB)
  const int gx = gridDim.x;
  const int nwg = gx * gridDim.y;
  int lin = blockIdx.x + blockIdx.y * gx;
  if ((nwg & 7) == 0) {
    const int chunk = nwg >> 3;
    lin = (lin & 7) * chunk + (lin >> 3);
  }
  const int bn = (lin % gx) * BN;
  const int bm = (lin / gx) * BM;

  f32x4 acc[FRM][FRN] = {};

  for (int k0 = 0; k0 < K; k0 += 32) {
    __syncthreads();  // previous compute done before LDS overwrite
    stage_tile<BM>(As_hi, Ahi, bm, K, k0, tid);
    if (ALO) stage_tile<BM>(As_lo, Alo, bm, K, k0, tid);
    stage_tile<BN>(Bs_hi, BhiT, bn, K, k0, tid);
    stage_tile<BN>(Bs_lo, BloT, bn, K, k0, tid);
    __syncthreads();  // vmcnt(0) drained by compiler before barrier

    f16x8 ah[FRM], al[FRM], bh[FRN], bl[FRN];
#pragma unroll
    for (int m = 0; m < FRM; ++m) {
      const int r = wr * WROWS + m * 16 + lr;
      ah[m] = frag_ld(As_hi, r, lk);
      if (ALO) al[m] = frag_ld(As_lo, r, lk);
    }
#pragma unroll
    for (int n = 0; n < FRN; ++n) {
      const int r = wc * WCOLS + n * 16 + lr;
      bh[n] = frag_ld(Bs_hi, r, lk);
      bl[n] = frag_ld(Bs_lo, r, lk);
    }
#pragma unroll
    for (int m = 0; m < FRM; ++m)
#pragma unroll
      for (int n = 0; n < FRN; ++n) {
        acc[m][n] = __builtin_amdgcn_mfma_f32_16x16x32_f16(ah[m], bh[n], acc[m][n], 0, 0, 0);
        acc[m][n] = __builtin_amdgcn_mfma_f32_16x16x32_f16(ah[m], bl[n], acc[m][n], 0, 0, 0);
        if (ALO)
          acc[m][n] = __builtin_amdgcn_mfma_f32_16x16x32_f16(al[m], bh[n], acc[m][n], 0, 0, 0);
      }
  }

  // epilogue
#pragma unroll
  for (int m = 0; m < FRM; ++m)
#pragma unroll
    for (int n = 0; n < FRN; ++n) {
      const int Cc = bn + wc * WCOLS + n * 16 + lr;
      float bv;
      if (EPI == 3) bv = (Cc < 512) ? bias[Cc] : bias2[Cc - 512];
      else          bv = bias[Cc];
#pragma unroll
      for (int q = 0; q < 4; ++q) {
        const int R = bm + wr * WROWS + m * 16 + lk * 4 + q;
        float v = acc[m][n][q] + bv;
        if (EPI == 0) {
          v = fmaxf(v, 0.0f);
          const _Float16 h = (_Float16)v;
          const _Float16 l = (_Float16)(v - (float)h);
          const size_t off = (size_t)R * N + kswz(Cc, R);
          ChiOut[off] = h;
          CloOut[off] = l;
        } else if (EPI == 1) {
          Cf32[(size_t)R * N + Cc] = 1.0f / (1.0f + expf(-v));
        } else if (EPI == 2) {
          Cf32[(size_t)R * N + Cc] = v;
        } else {  // EPI == 3: dual relu split output
          v = fmaxf(v, 0.0f);
          const _Float16 h = (_Float16)v;
          const _Float16 l = (_Float16)(v - (float)h);
          if (Cc < 512) {
            const size_t off = (size_t)R * 512 + kswz(Cc, R);
            ChiOut[off] = h;
            CloOut[off] = l;
          } else {
            const int c2 = Cc - 512;
            const size_t off = (size_t)R * 1024 + kswz(c2, R);
            Chi2[off] = h;
            Clo2[off] = l;
          }
        }
      }
    }
}

// ---------------------------------------------------------------------------
// weight conversion: w[K][N] f32 -> transposed split swizzled planes [N][K]
// ---------------------------------------------------------------------------
__global__ __launch_bounds__(256)
void wconv(const float* __restrict__ w, _Float16* __restrict__ hiT,
           _Float16* __restrict__ loT, int K, int N)
{
  __shared__ float tile[64][65];
  const int n0 = blockIdx.x * 64, k0 = blockIdx.y * 64;
  const int t = threadIdx.x;
  const int c = t & 63, r4 = t >> 6;
#pragma unroll
  for (int i = 0; i < 16; ++i) {
    const int r = r4 * 16 + i;
    tile[r][c] = w[(size_t)(k0 + r) * N + n0 + c];
  }
  __syncthreads();
#pragma unroll
  for (int i = 0; i < 16; ++i) {
    const int n = r4 * 16 + i;      // n-rel
    const int k = c;                // k-rel
    const float v = tile[k][n];
    const _Float16 h = (_Float16)v;
    const _Float16 l = (_Float16)(v - (float)h);
    const int R = n0 + n;
    const size_t off = (size_t)R * K + kswz(k0 + k, R);
    hiT[off] = h;
    loT[off] = l;
  }
}

// ---------------------------------------------------------------------------
// x conversion: x[M][512] f32 (one-hot, exact in fp16) -> swizzled hi plane
// ---------------------------------------------------------------------------
__global__ __launch_bounds__(256)
void xconv(const float* __restrict__ x, _Float16* __restrict__ hi)
{
  const int gid = blockIdx.x * 256 + threadIdx.x;  // M*64 slots
  const int R = gid >> 6, slot = gid & 63;
  const float4* p = (const float4*)(x + (size_t)R * 512 + slot * 8);
  const float4 a = p[0], b = p[1];
  f16x8 h;
  h[0] = (_Float16)a.x; h[1] = (_Float16)a.y; h[2] = (_Float16)a.z; h[3] = (_Float16)a.w;
  h[4] = (_Float16)b.x; h[5] = (_Float16)b.y; h[6] = (_Float16)b.z; h[7] = (_Float16)b.w;
  const int chunk = (slot >> 2) << 5;
  const int s = (slot & 3) ^ ((R >> 1) & 3);
  *(f16x8*)(hi + (size_t)R * 512 + chunk + s * 8) = h;
}

// ---------------------------------------------------------------------------
// Finalize (unchanged from the passing round-5 kernel)
// ---------------------------------------------------------------------------
__global__ __launch_bounds__(256)
void finalize_kernel(const float* __restrict__ x,
                     const float* __restrict__ truth,
                     const float* __restrict__ Pm,
                     const float* __restrict__ Wm,
                     float* __restrict__ o_truth,
                     float* __restrict__ o_xcf,
                     uint32_t ka0, uint32_t ka1,
                     uint32_t kb0, uint32_t kb1,
                     uint32_t kg0, uint32_t kg1)
{
  const int gid = blockIdx.x * 256 + threadIdx.x;
  const int b = gid >> 6;
  const int n = gid & 63;
  const size_t ro = (size_t)b * DD + (size_t)n * CC;

  {
    float4 t0 = *reinterpret_cast<const float4*>(truth + ro);
    float4 t1 = *reinterpret_cast<const float4*>(truth + ro + 4);
    *reinterpret_cast<float4*>(o_truth + ro) = t0;
    *reinterpret_cast<float4*>(o_truth + ro + 4) = t1;
  }

  float x8[8];
  {
    float4 a = *reinterpret_cast<const float4*>(x + ro);
    float4 c = *reinterpret_cast<const float4*>(x + ro + 4);
    x8[0] = a.x; x8[1] = a.y; x8[2] = a.z; x8[3] = a.w;
    x8[4] = c.x; x8[5] = c.y; x8[6] = c.z; x8[7] = c.w;
  }
  int curr = 0;
  {
    float xm = x8[0];
#pragma unroll
    for (int c = 1; c < 8; ++c) if (x8[c] > xm) { xm = x8[c]; curr = c; }
  }

  const uint32_t ia = (uint32_t)(b * NN + n);
  const float ua = jax_uniform(tf_bits_p(ka0, ka1, ia));
  const float ub = jax_uniform(tf_bits_p(kb0, kb1, ia));
  const float eaa = expf(-logf(-logf(ua)));
  const float ebb = expf(-logf(-logf(ub)));
  const float Pv = Pm[(size_t)b * NN + n];
  const float no = Pv * eaa / 0.7f;
  const float de = no + (1.0f - Pv) * ebb / 0.7f;
  const float prob = no / de;

  float g8[8];
#pragma unroll
  for (int c = 0; c < 8; ++c)
    g8[c] = -logf(-logf(jax_uniform(tf_bits_p(kg0, kg1, ia * 8u + (uint32_t)c))));

  float w8[8];
  {
    float4 a = *reinterpret_cast<const float4*>(Wm + ro);
    float4 c = *reinterpret_cast<const float4*>(Wm + ro + 4);
    w8[0] = a.x; w8[1] = a.y; w8[2] = a.z; w8[3] = a.w;
    w8[4] = c.x; w8[5] = c.y; w8[6] = c.z; w8[7] = c.w;
  }

  int diff = 0;
  if (n == 2) {
    float mx = w8[0];
#pragma unroll
    for (int c = 1; c < 8; ++c) mx = fmaxf(mx, w8[c]);
    float e[8], s = 0.0f;
#pragma unroll
    for (int c = 0; c < 8; ++c) { e[c] = expf(w8[c] - mx); s += e[c]; }
    float l2[8];
#pragma unroll
    for (int c = 0; c < 8; ++c)
      l2[c] = (logf(0.9f * (e[c] / s) + 0.0125f) + g8[c]) / 0.7f;
    float mx2 = l2[0];
#pragma unroll
    for (int c = 1; c < 8; ++c) mx2 = fmaxf(mx2, l2[c]);
    float e2[8], s2 = 0.0f;
#pragma unroll
    for (int c = 0; c < 8; ++c) { e2[c] = expf(l2[c] - mx2); s2 += e2[c]; }
    float bv = -1e30f; int am = 0;
#pragma unroll
    for (int c = 0; c < 8; ++c) {
      float ov = prob * (e2[c] / s2) + (1.0f - prob) * x8[c];
      if (ov > bv) { bv = ov; am = c; }
    }
    diff = am - curr;
  }
  diff = __shfl(diff, 2, 64);
  const bool cst = (diff == 0);
  const bool inc = (diff > 0);

  float p2 = prob;
  if (n == 7) {
    float pc = prob * (cst ? 0.0f : 1.0f) + (inc ? 1.0f : 0.0f);
    p2 = fminf(fmaxf(pc, 0.0f), 1.0f);
  }

  const bool causal = (n == 0) | (n == 5) | (n == 10);
  float lg[8];
#pragma unroll
  for (int c = 0; c < 8; ++c) {
    float m = 0.0f;
    if (causal) m = (c < curr) ? -100.0f : 1.0f;
    if (n == 7) m = (inc && (c < curr + 1)) ? -100.0f : 1.0f;
    lg[c] = w8[c] + m;
  }

  float mx = lg[0];
#pragma unroll
  for (int c = 1; c < 8; ++c) mx = fmaxf(mx, lg[c]);
  float e[8], s = 0.0f;
#pragma unroll
  for (int c = 0; c < 8; ++c) { e[c] = expf(lg[c] - mx); s += e[c]; }
  float l2[8];
#pragma unroll
  for (int c = 0; c < 8; ++c)
    l2[c] = (logf(0.9f * (e[c] / s) + 0.0125f) + g8[c]) / 0.7f;
  float mx2 = l2[0];
#pragma unroll
  for (int c = 1; c < 8; ++c) mx2 = fmaxf(mx2, l2[c]);
  float e2[8], s2 = 0.0f;
#pragma unroll
  for (int c = 0; c < 8; ++c) { e2[c] = expf(l2[c] - mx2); s2 += e2[c]; }

  float4 o0, o1;
  float* op = &o0.x;
#pragma unroll
  for (int c = 0; c < 4; ++c) op[c] = p2 * (e2[c] / s2) + (1.0f - p2) * x8[c];
  float* op1 = &o1.x;
#pragma unroll
  for (int c = 0; c < 4; ++c) op1[c] = p2 * (e2[c + 4] / s2) + (1.0f - p2) * x8[c + 4];
  *reinterpret_cast<float4*>(o_xcf + ro) = o0;
  *reinterpret_cast<float4*>(o_xcf + ro + 4) = o1;
}

// ---------------------------------------------------------------------------
// Launch
// ---------------------------------------------------------------------------
extern "C" void kernel_launch(void* const* d_in, const int* in_sizes, int n_in,
                              void* d_out, int out_size, void* d_ws, size_t ws_size,
                              hipStream_t stream)
{
  const float* x     = (const float*)d_in[0];
  const float* truth = (const float*)d_in[1];
  const float* sw1   = (const float*)d_in[2];
  const float* sb1   = (const float*)d_in[3];
  const float* sw2   = (const float*)d_in[4];
  const float* sb2   = (const float*)d_in[5];
  const float* pw1   = (const float*)d_in[6];
  const float* pb1   = (const float*)d_in[7];
  const float* pw2   = (const float*)d_in[8];
  const float* pb2   = (const float*)d_in[9];
  const float* pw3   = (const float*)d_in[10];
  const float* pb3   = (const float*)d_in[11];
  const float* pw4   = (const float*)d_in[12];
  const float* pb4   = (const float*)d_in[13];

  float* out      = (float*)d_out;
  float* o_truth  = out;                       // B*D f32
  float* o_xcf    = out + (size_t)BB * DD;     // B*D
  float* o_P      = o_xcf + (size_t)BB * DD;   // B*N
  float* o_W      = o_P + (size_t)BB * NN;     // B*D

  // -------- ws layout --------
  _Float16* wsb = (_Float16*)d_ws;
  size_t cur = 0;
  auto alloc = [&](size_t nelem) { _Float16* p = wsb + cur; cur += nelem; return p; };
  // merged B-plane for G1+G3: rows 0-511 = sw1 cols, rows 512-1535 = pw1 cols
  _Float16* sB_hi  = alloc((size_t)1536 * 512);
  _Float16* sB_lo  = alloc((size_t)1536 * 512);
  _Float16* sw2T_hi = alloc(64 * 512);    _Float16* sw2T_lo = alloc(64 * 512);
  _Float16* pw2T_hi = alloc(1024 * 1024); _Float16* pw2T_lo = alloc(1024 * 1024);
  _Float16* pw3T_hi = alloc(1024 * 1024); _Float16* pw3T_lo = alloc(1024 * 1024);
  _Float16* pw4T_hi = alloc(512 * 1024);  _Float16* pw4T_lo = alloc(512 * 1024);
  // R1: 32MB region. First holds x_hi(8MB)+s1_hi(8MB)+s1_lo(8MB); later h2.
  _Float16* R1 = alloc((size_t)16 * 1024 * 1024);
  _Float16* x_hi  = R1;
  _Float16* s1_hi = R1 + (size_t)BB * HSS;
  _Float16* s1_lo = s1_hi + (size_t)BB * HSS;
  _Float16* h2_hi = R1;
  _Float16* h2_lo = R1 + (size_t)BB * HPP;
  // R2: the truth+xcf region of d_out (32MB), free until finalize.
  _Float16* h1_hi = (_Float16*)d_out;
  _Float16* h1_lo = h1_hi + (size_t)BB * HPP;
  _Float16* h3_hi = h1_hi;
  _Float16* h3_lo = h1_lo;

  // JAX foldlike split (threefry_partitionable), verified round 5.
  uint32_t ka0, ka1, kb0, kb1, kg0, kg1;
  threefry2x32(0u, 42u, 0u, 0u, ka0, ka1);
  threefry2x32(0u, 42u, 0u, 1u, kb0, kb1);
  threefry2x32(0u, 42u, 0u, 2u, kg0, kg1);

  dim3 blk(256);

  // -------- conversions --------
  // sw1 -> rows 0-511 of merged plane; pw1 -> rows 512-1535
  wconv<<<dim3(512 / 64, 512 / 64), blk, 0, stream>>>(sw1, sB_hi, sB_lo, 512, 512);
  wconv<<<dim3(1024 / 64, 512 / 64), blk, 0, stream>>>(
      pw1, sB_hi + (size_t)512 * 512, sB_lo + (size_t)512 * 512, 512, 1024);
  wconv<<<dim3(64 / 64, 512 / 64), blk, 0, stream>>>(sw2, sw2T_hi, sw2T_lo, 512, 64);
  wconv<<<dim3(1024 / 64, 1024 / 64), blk, 0, stream>>>(pw2, pw2T_hi, pw2T_lo, 1024, 1024);
  wconv<<<dim3(1024 / 64, 1024 / 64), blk, 0, stream>>>(pw3, pw3T_hi, pw3T_lo, 1024, 1024);
  wconv<<<dim3(512 / 64, 1024 / 64), blk, 0, stream>>>(pw4, pw4T_hi, pw4T_lo, 1024, 512);
  xconv<<<dim3(BB * 64 / 256), blk, 0, stream>>>(x, x_hi);

  // -------- GEMM chain --------
  // G1+G3 merged: [s1 | h1] = relu(x @ [sw1|pw1] + [sb1|pb1])  (no A-lo)
  gemm_mfma<128, 64, 0, 3><<<dim3(1536 / 64, BB / 128), blk, 0, stream>>>(
      x_hi, nullptr, sB_hi, sB_lo, sb1, s1_hi, s1_lo, nullptr, BB, 1536, DD,
      pb1, h1_hi, h1_lo);
  // G2: P = sigmoid(s1@sw2+sb2)
  gemm_mfma<128, 64, 1, 1><<<dim3(NN / 64, BB / 128), blk, 0, stream>>>(
      s1_hi, s1_lo, sw2T_hi, sw2T_lo, sb2, nullptr, nullptr, o_P, BB, NN, HSS,
      nullptr, nullptr, nullptr);
  // G4: h2 = relu(h1@pw2+pb2) -> R1 (x,s1 dead)
  gemm_mfma<128, 64, 1, 0><<<dim3(HPP / 64, BB / 128), blk, 0, stream>>>(
      h1_hi, h1_lo, pw2T_hi, pw2T_lo, pb2, h2_hi, h2_lo, nullptr, BB, HPP, HPP,
      nullptr, nullptr, nullptr);
  // G5: h3 = relu(h2@pw3+pb3) -> R2 (over h1)
  gemm_mfma<128, 64, 1, 0><<<dim3(HPP / 64, BB / 128), blk, 0, stream>>>(
      h2_hi, h2_lo, pw3T_hi, pw3T_lo, pb3, h3_hi, h3_lo, nullptr, BB, HPP, HPP,
      nullptr, nullptr, nullptr);
  // G6: W = h3@pw4+pb4 -> o_W (f32)
  gemm_mfma<128, 64, 1, 2><<<dim3(DD / 64, BB / 128), blk, 0, stream>>>(
      h3_hi, h3_lo, pw4T_hi, pw4T_lo, pb4, nullptr, nullptr, o_W, BB, DD, HPP,
      nullptr, nullptr, nullptr);

  // -------- finalize (writes o_truth/o_xcf over R2 after G6 consumed h3) ----
  finalize_kernel<<<dim3(BB * NN / 256), blk, 0, stream>>>(
      x, truth, o_P, o_W, o_truth, o_xcf,
      ka0, ka1, kb0, kb1, kg0, kg1);
}

// Round 14
// 344.439 us; speedup vs baseline: 1.0650x; 1.0650x over previous
//
#include <hip/hip_runtime.h>
#include <stdint.h>

// ---------------------------------------------------------------------------
// Sizes (fixed by the reference)
// ---------------------------------------------------------------------------
#define BB 8192
#define NN 64
#define CC 8
#define DD 512   // N*C
#define HPP 1024
#define HSS 512

typedef _Float16 f16x8 __attribute__((ext_vector_type(8)));
typedef float f32x4 __attribute__((ext_vector_type(4)));

// ---------------------------------------------------------------------------
// JAX threefry2x32 (exact) — partitionable variant (verified round 5)
// ---------------------------------------------------------------------------
__host__ __device__ __forceinline__ void threefry2x32(
    uint32_t k0, uint32_t k1, uint32_t x0, uint32_t x1,
    uint32_t& o0, uint32_t& o1)
{
  const uint32_t ks2 = k0 ^ k1 ^ 0x1BD11BDAu;
#define TFR(r) { x0 += x1; x1 = (x1 << (r)) | (x1 >> (32 - (r))); x1 ^= x0; }
  x0 += k0; x1 += k1;
  TFR(13) TFR(15) TFR(26) TFR(6)
  x0 += k1;  x1 += ks2 + 1u;
  TFR(17) TFR(29) TFR(16) TFR(24)
  x0 += ks2; x1 += k0 + 2u;
  TFR(13) TFR(15) TFR(26) TFR(6)
  x0 += k0;  x1 += k1 + 3u;
  TFR(17) TFR(29) TFR(16) TFR(24)
  x0 += k1;  x1 += ks2 + 4u;
  TFR(13) TFR(15) TFR(26) TFR(6)
  x0 += ks2; x1 += k0 + 5u;
#undef TFR
  o0 = x0; o1 = x1;
}

__device__ __forceinline__ uint32_t tf_bits_p(uint32_t k0, uint32_t k1,
                                              uint32_t idx)
{
  uint32_t o0, o1;
  threefry2x32(k0, k1, 0u, idx, o0, o1);
  return o0 ^ o1;
}

__device__ __forceinline__ float jax_uniform(uint32_t bits)
{
  const float f = __uint_as_float((bits >> 9) | 0x3f800000u) - 1.0f;
  return fmaxf(1e-8f, f + 1e-8f);
}

// ---------------------------------------------------------------------------
// Swizzled split-fp16 plane layout (validated round 8: bank conflicts = 0).
//   kswz(k, r) = chunk(k) | ((((k>>3) ^ (r>>1)) & 3) << 3) | (k & 7)
// ---------------------------------------------------------------------------
__device__ __forceinline__ int kswz(int k, int r)
{
  return (k & ~31) | ((((k >> 3) ^ (r >> 1)) & 3) << 3) | (k & 7);
}

// async 16B global -> LDS copy (direct-to-LDS DMA)
__device__ __forceinline__ void async_copy16(void* lds, const void* g)
{
  __builtin_amdgcn_global_load_lds(
      (const __attribute__((address_space(1))) unsigned int*)g,
      (__attribute__((address_space(3))) unsigned int*)lds,
      16, 0, 0);
}

// stage a ROWSx32 fp16 tile (pre-swizzled global) into LDS, linear copy
template<int ROWS>
__device__ __forceinline__ void stage_tile(_Float16* lds, const _Float16* g,
                                           int row0, int ldK, int k0, int tid)
{
  constexpr int SLOTS = ROWS * 4;  // 16B slots
#pragma unroll
  for (int s0 = 0; s0 < SLOTS; s0 += 256) {
    const int s = s0 + tid;
    const char* gp = (const char*)(g + (size_t)(row0 + (s >> 2)) * ldK + k0)
                     + (s & 3) * 16;
    async_copy16((char*)lds + (size_t)s * 16, gp);
  }
}

// read one 16x32 MFMA fragment row-slice from a swizzled LDS plane
__device__ __forceinline__ f16x8 frag_ld(const _Float16* base, int row, int lk)
{
  const int off = row * 32 + (((lk ^ (row >> 1)) & 3) << 3);
  return *(const f16x8*)(base + off);
}

// ---------------------------------------------------------------------------
// Split-fp16 MFMA GEMM.  C[M,N] = act(A[M,K] @ B[K,N] + bias)
// Round-13: BN reverted to 128 (round-12 BN=64 HURT: MfmaUtil 38->29,
// dur 57->74us — occupancy was not the limiter; arithmetic intensity was).
// Keeps round-12's G1+G3 merge (EPI=3 dual output, verified correct).
// EPI: 0 = relu+split planes; 1 = f32 sigmoid; 2 = f32 none;
//      3 = dual relu+split (cols<512 -> C1/N=512/bias1, else C2/N=1024/bias2)
// ---------------------------------------------------------------------------
template<int BM, int BN, int ALO, int EPI>
__global__ __launch_bounds__(256, 2)
void gemm_mfma(const _Float16* __restrict__ Ahi, const _Float16* __restrict__ Alo,
               const _Float16* __restrict__ BhiT, const _Float16* __restrict__ BloT,
               const float* __restrict__ bias,
               _Float16* __restrict__ ChiOut, _Float16* __restrict__ CloOut,
               float* __restrict__ Cf32,
               int M, int N, int K,
               const float* __restrict__ bias2,
               _Float16* __restrict__ Chi2, _Float16* __restrict__ Clo2)
{
  __shared__ __align__(16) _Float16 As_hi[BM * 32];
  __shared__ __align__(16) _Float16 As_lo[ALO ? BM * 32 : 8];
  __shared__ __align__(16) _Float16 Bs_hi[BN * 32];
  __shared__ __align__(16) _Float16 Bs_lo[BN * 32];

  const int tid = threadIdx.x;
  const int wid = tid >> 6, lane = tid & 63;
  const int wr = wid >> 1, wc = wid & 1;
  constexpr int WROWS = BM / 2, WCOLS = BN / 2;
  constexpr int FRM = WROWS / 16, FRN = WCOLS / 16;
  const int lr = lane & 15, lk = lane >> 4;

  // T1 XCD-aware chunked swizzle (validated round 9: FETCH 133->33MB)
  const int gx = gridDim.x;
  const int nwg = gx * gridDim.y;
  int lin = blockIdx.x + blockIdx.y * gx;
  if ((nwg & 7) == 0) {
    const int chunk = nwg >> 3;
    lin = (lin & 7) * chunk + (lin >> 3);
  }
  const int bn = (lin % gx) * BN;
  const int bm = (lin / gx) * BM;

  f32x4 acc[FRM][FRN] = {};

  for (int k0 = 0; k0 < K; k0 += 32) {
    __syncthreads();  // previous compute done before LDS overwrite
    stage_tile<BM>(As_hi, Ahi, bm, K, k0, tid);
    if (ALO) stage_tile<BM>(As_lo, Alo, bm, K, k0, tid);
    stage_tile<BN>(Bs_hi, BhiT, bn, K, k0, tid);
    stage_tile<BN>(Bs_lo, BloT, bn, K, k0, tid);
    __syncthreads();  // vmcnt(0) drained by compiler before barrier

    f16x8 ah[FRM], al[FRM], bh[FRN], bl[FRN];
#pragma unroll
    for (int m = 0; m < FRM; ++m) {
      const int r = wr * WROWS + m * 16 + lr;
      ah[m] = frag_ld(As_hi, r, lk);
      if (ALO) al[m] = frag_ld(As_lo, r, lk);
    }
#pragma unroll
    for (int n = 0; n < FRN; ++n) {
      const int r = wc * WCOLS + n * 16 + lr;
      bh[n] = frag_ld(Bs_hi, r, lk);
      bl[n] = frag_ld(Bs_lo, r, lk);
    }
#pragma unroll
    for (int m = 0; m < FRM; ++m)
#pragma unroll
      for (int n = 0; n < FRN; ++n) {
        acc[m][n] = __builtin_amdgcn_mfma_f32_16x16x32_f16(ah[m], bh[n], acc[m][n], 0, 0, 0);
        acc[m][n] = __builtin_amdgcn_mfma_f32_16x16x32_f16(ah[m], bl[n], acc[m][n], 0, 0, 0);
        if (ALO)
          acc[m][n] = __builtin_amdgcn_mfma_f32_16x16x32_f16(al[m], bh[n], acc[m][n], 0, 0, 0);
      }
  }

  // epilogue
#pragma unroll
  for (int m = 0; m < FRM; ++m)
#pragma unroll
    for (int n = 0; n < FRN; ++n) {
      const int Cc = bn + wc * WCOLS + n * 16 + lr;
      float bv;
      if (EPI == 3) bv = (Cc < 512) ? bias[Cc] : bias2[Cc - 512];
      else          bv = bias[Cc];
#pragma unroll
      for (int q = 0; q < 4; ++q) {
        const int R = bm + wr * WROWS + m * 16 + lk * 4 + q;
        float v = acc[m][n][q] + bv;
        if (EPI == 0) {
          v = fmaxf(v, 0.0f);
          const _Float16 h = (_Float16)v;
          const _Float16 l = (_Float16)(v - (float)h);
          const size_t off = (size_t)R * N + kswz(Cc, R);
          ChiOut[off] = h;
          CloOut[off] = l;
        } else if (EPI == 1) {
          Cf32[(size_t)R * N + Cc] = 1.0f / (1.0f + expf(-v));
        } else if (EPI == 2) {
          Cf32[(size_t)R * N + Cc] = v;
        } else {  // EPI == 3: dual relu split output
          v = fmaxf(v, 0.0f);
          const _Float16 h = (_Float16)v;
          const _Float16 l = (_Float16)(v - (float)h);
          if (Cc < 512) {
            const size_t off = (size_t)R * 512 + kswz(Cc, R);
            ChiOut[off] = h;
            CloOut[off] = l;
          } else {
            const int c2 = Cc - 512;
            const size_t off = (size_t)R * 1024 + kswz(c2, R);
            Chi2[off] = h;
            Clo2[off] = l;
          }
        }
      }
    }
}

// ---------------------------------------------------------------------------
// weight conversion: w[K][N] f32 -> transposed split swizzled planes [N][K]
// ---------------------------------------------------------------------------
__global__ __launch_bounds__(256)
void wconv(const float* __restrict__ w, _Float16* __restrict__ hiT,
           _Float16* __restrict__ loT, int K, int N)
{
  __shared__ float tile[64][65];
  const int n0 = blockIdx.x * 64, k0 = blockIdx.y * 64;
  const int t = threadIdx.x;
  const int c = t & 63, r4 = t >> 6;
#pragma unroll
  for (int i = 0; i < 16; ++i) {
    const int r = r4 * 16 + i;
    tile[r][c] = w[(size_t)(k0 + r) * N + n0 + c];
  }
  __syncthreads();
#pragma unroll
  for (int i = 0; i < 16; ++i) {
    const int n = r4 * 16 + i;      // n-rel
    const int k = c;                // k-rel
    const float v = tile[k][n];
    const _Float16 h = (_Float16)v;
    const _Float16 l = (_Float16)(v - (float)h);
    const int R = n0 + n;
    const size_t off = (size_t)R * K + kswz(k0 + k, R);
    hiT[off] = h;
    loT[off] = l;
  }
}

// ---------------------------------------------------------------------------
// x conversion: x[M][512] f32 (one-hot, exact in fp16) -> swizzled hi plane
// ---------------------------------------------------------------------------
__global__ __launch_bounds__(256)
void xconv(const float* __restrict__ x, _Float16* __restrict__ hi)
{
  const int gid = blockIdx.x * 256 + threadIdx.x;  // M*64 slots
  const int R = gid >> 6, slot = gid & 63;
  const float4* p = (const float4*)(x + (size_t)R * 512 + slot * 8);
  const float4 a = p[0], b = p[1];
  f16x8 h;
  h[0] = (_Float16)a.x; h[1] = (_Float16)a.y; h[2] = (_Float16)a.z; h[3] = (_Float16)a.w;
  h[4] = (_Float16)b.x; h[5] = (_Float16)b.y; h[6] = (_Float16)b.z; h[7] = (_Float16)b.w;
  const int chunk = (slot >> 2) << 5;
  const int s = (slot & 3) ^ ((R >> 1) & 3);
  *(f16x8*)(hi + (size_t)R * 512 + chunk + s * 8) = h;
}

// ---------------------------------------------------------------------------
// Finalize (unchanged from the passing round-5 kernel)
// ---------------------------------------------------------------------------
__global__ __launch_bounds__(256)
void finalize_kernel(const float* __restrict__ x,
                     const float* __restrict__ truth,
                     const float* __restrict__ Pm,
                     const float* __restrict__ Wm,
                     float* __restrict__ o_truth,
                     float* __restrict__ o_xcf,
                     uint32_t ka0, uint32_t ka1,
                     uint32_t kb0, uint32_t kb1,
                     uint32_t kg0, uint32_t kg1)
{
  const int gid = blockIdx.x * 256 + threadIdx.x;
  const int b = gid >> 6;
  const int n = gid & 63;
  const size_t ro = (size_t)b * DD + (size_t)n * CC;

  {
    float4 t0 = *reinterpret_cast<const float4*>(truth + ro);
    float4 t1 = *reinterpret_cast<const float4*>(truth + ro + 4);
    *reinterpret_cast<float4*>(o_truth + ro) = t0;
    *reinterpret_cast<float4*>(o_truth + ro + 4) = t1;
  }

  float x8[8];
  {
    float4 a = *reinterpret_cast<const float4*>(x + ro);
    float4 c = *reinterpret_cast<const float4*>(x + ro + 4);
    x8[0] = a.x; x8[1] = a.y; x8[2] = a.z; x8[3] = a.w;
    x8[4] = c.x; x8[5] = c.y; x8[6] = c.z; x8[7] = c.w;
  }
  int curr = 0;
  {
    float xm = x8[0];
#pragma unroll
    for (int c = 1; c < 8; ++c) if (x8[c] > xm) { xm = x8[c]; curr = c; }
  }

  const uint32_t ia = (uint32_t)(b * NN + n);
  const float ua = jax_uniform(tf_bits_p(ka0, ka1, ia));
  const float ub = jax_uniform(tf_bits_p(kb0, kb1, ia));
  const float eaa = expf(-logf(-logf(ua)));
  const float ebb = expf(-logf(-logf(ub)));
  const float Pv = Pm[(size_t)b * NN + n];
  const float no = Pv * eaa / 0.7f;
  const float de = no + (1.0f - Pv) * ebb / 0.7f;
  const float prob = no / de;

  float g8[8];
#pragma unroll
  for (int c = 0; c < 8; ++c)
    g8[c] = -logf(-logf(jax_uniform(tf_bits_p(kg0, kg1, ia * 8u + (uint32_t)c))));

  float w8[8];
  {
    float4 a = *reinterpret_cast<const float4*>(Wm + ro);
    float4 c = *reinterpret_cast<const float4*>(Wm + ro + 4);
    w8[0] = a.x; w8[1] = a.y; w8[2] = a.z; w8[3] = a.w;
    w8[4] = c.x; w8[5] = c.y; w8[6] = c.z; w8[7] = c.w;
  }

  int diff = 0;
  if (n == 2) {
    float mx = w8[0];
#pragma unroll
    for (int c = 1; c < 8; ++c) mx = fmaxf(mx, w8[c]);
    float e[8], s = 0.0f;
#pragma unroll
    for (int c = 0; c < 8; ++c) { e[c] = expf(w8[c] - mx); s += e[c]; }
    float l2[8];
#pragma unroll
    for (int c = 0; c < 8; ++c)
      l2[c] = (logf(0.9f * (e[c] / s) + 0.0125f) + g8[c]) / 0.7f;
    float mx2 = l2[0];
#pragma unroll
    for (int c = 1; c < 8; ++c) mx2 = fmaxf(mx2, l2[c]);
    float e2[8], s2 = 0.0f;
#pragma unroll
    for (int c = 0; c < 8; ++c) { e2[c] = expf(l2[c] - mx2); s2 += e2[c]; }
    float bv = -1e30f; int am = 0;
#pragma unroll
    for (int c = 0; c < 8; ++c) {
      float ov = prob * (e2[c] / s2) + (1.0f - prob) * x8[c];
      if (ov > bv) { bv = ov; am = c; }
    }
    diff = am - curr;
  }
  diff = __shfl(diff, 2, 64);
  const bool cst = (diff == 0);
  const bool inc = (diff > 0);

  float p2 = prob;
  if (n == 7) {
    float pc = prob * (cst ? 0.0f : 1.0f) + (inc ? 1.0f : 0.0f);
    p2 = fminf(fmaxf(pc, 0.0f), 1.0f);
  }

  const bool causal = (n == 0) | (n == 5) | (n == 10);
  float lg[8];
#pragma unroll
  for (int c = 0; c < 8; ++c) {
    float m = 0.0f;
    if (causal) m = (c < curr) ? -100.0f : 1.0f;
    if (n == 7) m = (inc && (c < curr + 1)) ? -100.0f : 1.0f;
    lg[c] = w8[c] + m;
  }

  float mx = lg[0];
#pragma unroll
  for (int c = 1; c < 8; ++c) mx = fmaxf(mx, lg[c]);
  float e[8], s = 0.0f;
#pragma unroll
  for (int c = 0; c < 8; ++c) { e[c] = expf(lg[c] - mx); s += e[c]; }
  float l2[8];
#pragma unroll
  for (int c = 0; c < 8; ++c)
    l2[c] = (logf(0.9f * (e[c] / s) + 0.0125f) + g8[c]) / 0.7f;
  float mx2 = l2[0];
#pragma unroll
  for (int c = 1; c < 8; ++c) mx2 = fmaxf(mx2, l2[c]);
  float e2[8], s2 = 0.0f;
#pragma unroll
  for (int c = 0; c < 8; ++c) { e2[c] = expf(l2[c] - mx2); s2 += e2[c]; }

  float4 o0, o1;
  float* op = &o0.x;
#pragma unroll
  for (int c = 0; c < 4; ++c) op[c] = p2 * (e2[c] / s2) + (1.0f - p2) * x8[c];
  float* op1 = &o1.x;
#pragma unroll
  for (int c = 0; c < 4; ++c) op1[c] = p2 * (e2[c + 4] / s2) + (1.0f - p2) * x8[c + 4];
  *reinterpret_cast<float4*>(o_xcf + ro) = o0;
  *reinterpret_cast<float4*>(o_xcf + ro + 4) = o1;
}

// ---------------------------------------------------------------------------
// Launch
// ---------------------------------------------------------------------------
extern "C" void kernel_launch(void* const* d_in, const int* in_sizes, int n_in,
                              void* d_out, int out_size, void* d_ws, size_t ws_size,
                              hipStream_t stream)
{
  const float* x     = (const float*)d_in[0];
  const float* truth = (const float*)d_in[1];
  const float* sw1   = (const float*)d_in[2];
  const float* sb1   = (const float*)d_in[3];
  const float* sw2   = (const float*)d_in[4];
  const float* sb2   = (const float*)d_in[5];
  const float* pw1   = (const float*)d_in[6];
  const float* pb1   = (const float*)d_in[7];
  const float* pw2   = (const float*)d_in[8];
  const float* pb2   = (const float*)d_in[9];
  const float* pw3   = (const float*)d_in[10];
  const float* pb3   = (const float*)d_in[11];
  const float* pw4   = (const float*)d_in[12];
  const float* pb4   = (const float*)d_in[13];

  float* out      = (float*)d_out;
  float* o_truth  = out;                       // B*D f32
  float* o_xcf    = out + (size_t)BB * DD;     // B*D
  float* o_P      = o_xcf + (size_t)BB * DD;   // B*N
  float* o_W      = o_P + (size_t)BB * NN;     // B*D

  // -------- ws layout --------
  _Float16* wsb = (_Float16*)d_ws;
  size_t cur = 0;
  auto alloc = [&](size_t nelem) { _Float16* p = wsb + cur; cur += nelem; return p; };
  // merged B-plane for G1+G3: rows 0-511 = sw1 cols, rows 512-1535 = pw1 cols
  _Float16* sB_hi  = alloc((size_t)1536 * 512);
  _Float16* sB_lo  = alloc((size_t)1536 * 512);
  _Float16* sw2T_hi = alloc(64 * 512);    _Float16* sw2T_lo = alloc(64 * 512);
  _Float16* pw2T_hi = alloc(1024 * 1024); _Float16* pw2T_lo = alloc(1024 * 1024);
  _Float16* pw3T_hi = alloc(1024 * 1024); _Float16* pw3T_lo = alloc(1024 * 1024);
  _Float16* pw4T_hi = alloc(512 * 1024);  _Float16* pw4T_lo = alloc(512 * 1024);
  // R1: 32MB region. First holds x_hi(8MB)+s1_hi(8MB)+s1_lo(8MB); later h2.
  _Float16* R1 = alloc((size_t)16 * 1024 * 1024);
  _Float16* x_hi  = R1;
  _Float16* s1_hi = R1 + (size_t)BB * HSS;
  _Float16* s1_lo = s1_hi + (size_t)BB * HSS;
  _Float16* h2_hi = R1;
  _Float16* h2_lo = R1 + (size_t)BB * HPP;
  // R2: the truth+xcf region of d_out (32MB), free until finalize.
  _Float16* h1_hi = (_Float16*)d_out;
  _Float16* h1_lo = h1_hi + (size_t)BB * HPP;
  _Float16* h3_hi = h1_hi;
  _Float16* h3_lo = h1_lo;

  // JAX foldlike split (threefry_partitionable), verified round 5.
  uint32_t ka0, ka1, kb0, kb1, kg0, kg1;
  threefry2x32(0u, 42u, 0u, 0u, ka0, ka1);
  threefry2x32(0u, 42u, 0u, 1u, kb0, kb1);
  threefry2x32(0u, 42u, 0u, 2u, kg0, kg1);

  dim3 blk(256);

  // -------- conversions --------
  // sw1 -> rows 0-511 of merged plane; pw1 -> rows 512-1535
  wconv<<<dim3(512 / 64, 512 / 64), blk, 0, stream>>>(sw1, sB_hi, sB_lo, 512, 512);
  wconv<<<dim3(1024 / 64, 512 / 64), blk, 0, stream>>>(
      pw1, sB_hi + (size_t)512 * 512, sB_lo + (size_t)512 * 512, 512, 1024);
  wconv<<<dim3(64 / 64, 512 / 64), blk, 0, stream>>>(sw2, sw2T_hi, sw2T_lo, 512, 64);
  wconv<<<dim3(1024 / 64, 1024 / 64), blk, 0, stream>>>(pw2, pw2T_hi, pw2T_lo, 1024, 1024);
  wconv<<<dim3(1024 / 64, 1024 / 64), blk, 0, stream>>>(pw3, pw3T_hi, pw3T_lo, 1024, 1024);
  wconv<<<dim3(512 / 64, 1024 / 64), blk, 0, stream>>>(pw4, pw4T_hi, pw4T_lo, 1024, 512);
  xconv<<<dim3(BB * 64 / 256), blk, 0, stream>>>(x, x_hi);

  // -------- GEMM chain --------
  // G1+G3 merged: [s1 | h1] = relu(x @ [sw1|pw1] + [sb1|pb1])  (no A-lo)
  gemm_mfma<128, 128, 0, 3><<<dim3(1536 / 128, BB / 128), blk, 0, stream>>>(
      x_hi, nullptr, sB_hi, sB_lo, sb1, s1_hi, s1_lo, nullptr, BB, 1536, DD,
      pb1, h1_hi, h1_lo);
  // G2: P = sigmoid(s1@sw2+sb2)
  gemm_mfma<128, 64, 1, 1><<<dim3(NN / 64, BB / 128), blk, 0, stream>>>(
      s1_hi, s1_lo, sw2T_hi, sw2T_lo, sb2, nullptr, nullptr, o_P, BB, NN, HSS,
      nullptr, nullptr, nullptr);
  // G4: h2 = relu(h1@pw2+pb2) -> R1 (x,s1 dead)
  gemm_mfma<128, 128, 1, 0><<<dim3(HPP / 128, BB / 128), blk, 0, stream>>>(
      h1_hi, h1_lo, pw2T_hi, pw2T_lo, pb2, h2_hi, h2_lo, nullptr, BB, HPP, HPP,
      nullptr, nullptr, nullptr);
  // G5: h3 = relu(h2@pw3+pb3) -> R2 (over h1)
  gemm_mfma<128, 128, 1, 0><<<dim3(HPP / 128, BB / 128), blk, 0, stream>>>(
      h2_hi, h2_lo, pw3T_hi, pw3T_lo, pb3, h3_hi, h3_lo, nullptr, BB, HPP, HPP,
      nullptr, nullptr, nullptr);
  // G6: W = h3@pw4+pb4 -> o_W (f32)
  gemm_mfma<128, 128, 1, 2><<<dim3(DD / 128, BB / 128), blk, 0, stream>>>(
      h3_hi, h3_lo, pw4T_hi, pw4T_lo, pb4, nullptr, nullptr, o_W, BB, DD, HPP,
      nullptr, nullptr, nullptr);

  // -------- finalize (writes o_truth/o_xcf over R2 after G6 consumed h3) ----
  finalize_kernel<<<dim3(BB * NN / 256), blk, 0, stream>>>(
      x, truth, o_P, o_W, o_truth, o_xcf,
      ka0, ka1, kb0, kb1, kg0, kg1);
}

// Round 15
// 326.435 us; speedup vs baseline: 1.1237x; 1.0552x over previous
//
#include <hip/hip_runtime.h>
#include <stdint.h>

// ---------------------------------------------------------------------------
// Sizes (fixed by the reference)
// ---------------------------------------------------------------------------
#define BB 8192
#define NN 64
#define CC 8
#define DD 512   // N*C
#define HPP 1024
#define HSS 512

typedef _Float16 f16x8 __attribute__((ext_vector_type(8)));
typedef float f32x4 __attribute__((ext_vector_type(4)));

// ---------------------------------------------------------------------------
// JAX threefry2x32 (exact) — partitionable variant (verified round 5)
// ---------------------------------------------------------------------------
__host__ __device__ __forceinline__ void threefry2x32(
    uint32_t k0, uint32_t k1, uint32_t x0, uint32_t x1,
    uint32_t& o0, uint32_t& o1)
{
  const uint32_t ks2 = k0 ^ k1 ^ 0x1BD11BDAu;
#define TFR(r) { x0 += x1; x1 = (x1 << (r)) | (x1 >> (32 - (r))); x1 ^= x0; }
  x0 += k0; x1 += k1;
  TFR(13) TFR(15) TFR(26) TFR(6)
  x0 += k1;  x1 += ks2 + 1u;
  TFR(17) TFR(29) TFR(16) TFR(24)
  x0 += ks2; x1 += k0 + 2u;
  TFR(13) TFR(15) TFR(26) TFR(6)
  x0 += k0;  x1 += k1 + 3u;
  TFR(17) TFR(29) TFR(16) TFR(24)
  x0 += k1;  x1 += ks2 + 4u;
  TFR(13) TFR(15) TFR(26) TFR(6)
  x0 += ks2; x1 += k0 + 5u;
#undef TFR
  o0 = x0; o1 = x1;
}

__device__ __forceinline__ uint32_t tf_bits_p(uint32_t k0, uint32_t k1,
                                              uint32_t idx)
{
  uint32_t o0, o1;
  threefry2x32(k0, k1, 0u, idx, o0, o1);
  return o0 ^ o1;
}

__device__ __forceinline__ float jax_uniform(uint32_t bits)
{
  const float f = __uint_as_float((bits >> 9) | 0x3f800000u) - 1.0f;
  return fmaxf(1e-8f, f + 1e-8f);
}

// ---------------------------------------------------------------------------
// Swizzled split-fp16 plane layout (validated round 8: bank conflicts = 0).
//   kswz(k, r) = chunk(k) | ((((k>>3) ^ (r>>1)) & 3) << 3) | (k & 7)
// ---------------------------------------------------------------------------
__device__ __forceinline__ int kswz(int k, int r)
{
  return (k & ~31) | ((((k >> 3) ^ (r >> 1)) & 3) << 3) | (k & 7);
}

// async 16B global -> LDS copy (direct-to-LDS DMA)
__device__ __forceinline__ void async_copy16(void* lds, const void* g)
{
  __builtin_amdgcn_global_load_lds(
      (const __attribute__((address_space(1))) unsigned int*)g,
      (__attribute__((address_space(3))) unsigned int*)lds,
      16, 0, 0);
}

// stage a ROWSx32 fp16 tile (pre-swizzled global) into LDS, linear copy
template<int ROWS>
__device__ __forceinline__ void stage_tile(_Float16* lds, const _Float16* g,
                                           int row0, int ldK, int k0, int tid)
{
  constexpr int SLOTS = ROWS * 4;  // 16B slots
#pragma unroll
  for (int s0 = 0; s0 < SLOTS; s0 += 256) {
    const int s = s0 + tid;
    const char* gp = (const char*)(g + (size_t)(row0 + (s >> 2)) * ldK + k0)
                     + (s & 3) * 16;
    async_copy16((char*)lds + (size_t)s * 16, gp);
  }
}

// read one 16x32 MFMA fragment row-slice from a swizzled LDS plane
__device__ __forceinline__ f16x8 frag_ld(const _Float16* base, int row, int lk)
{
  const int off = row * 32 + (((lk ^ (row >> 1)) & 3) << 3);
  return *(const f16x8*)(base + off);
}

// ---------------------------------------------------------------------------
// Split-fp16 MFMA GEMM.  C[M,N] = act(A[M,K] @ B[K,N] + bias)
// Round-15: BK=64 (two 32-K sub-steps per barrier pair) — halves the
// vmcnt(0)+barrier drains per K. LDS 64KB -> still 2 blocks/CU.
// EPI: 0 = relu+split planes; 1 = f32 sigmoid; 2 = f32 none;
//      3 = dual relu+split (cols<512 -> C1/N=512/bias1, else C2/N=1024/bias2)
// ---------------------------------------------------------------------------
template<int BM, int BN, int ALO, int EPI>
__global__ __launch_bounds__(256, 2)
void gemm_mfma(const _Float16* __restrict__ Ahi, const _Float16* __restrict__ Alo,
               const _Float16* __restrict__ BhiT, const _Float16* __restrict__ BloT,
               const float* __restrict__ bias,
               _Float16* __restrict__ ChiOut, _Float16* __restrict__ CloOut,
               float* __restrict__ Cf32,
               int M, int N, int K,
               const float* __restrict__ bias2,
               _Float16* __restrict__ Chi2, _Float16* __restrict__ Clo2)
{
  __shared__ __align__(16) _Float16 As_hi[2][BM * 32];
  __shared__ __align__(16) _Float16 As_lo[ALO ? 2 : 1][ALO ? BM * 32 : 8];
  __shared__ __align__(16) _Float16 Bs_hi[2][BN * 32];
  __shared__ __align__(16) _Float16 Bs_lo[2][BN * 32];

  const int tid = threadIdx.x;
  const int wid = tid >> 6, lane = tid & 63;
  const int wr = wid >> 1, wc = wid & 1;
  constexpr int WROWS = BM / 2, WCOLS = BN / 2;
  constexpr int FRM = WROWS / 16, FRN = WCOLS / 16;
  const int lr = lane & 15, lk = lane >> 4;

  // T1 XCD-aware chunked swizzle (validated round 9: FETCH 133->33MB)
  const int gx = gridDim.x;
  const int nwg = gx * gridDim.y;
  int lin = blockIdx.x + blockIdx.y * gx;
  if ((nwg & 7) == 0) {
    const int chunk = nwg >> 3;
    lin = (lin & 7) * chunk + (lin >> 3);
  }
  const int bn = (lin % gx) * BN;
  const int bm = (lin / gx) * BM;

  f32x4 acc[FRM][FRN] = {};

  for (int k0 = 0; k0 < K; k0 += 64) {
    __syncthreads();  // previous compute done before LDS overwrite
#pragma unroll
    for (int h = 0; h < 2; ++h) {
      stage_tile<BM>(As_hi[h], Ahi, bm, K, k0 + 32 * h, tid);
      if (ALO) stage_tile<BM>(As_lo[h], Alo, bm, K, k0 + 32 * h, tid);
      stage_tile<BN>(Bs_hi[h], BhiT, bn, K, k0 + 32 * h, tid);
      stage_tile<BN>(Bs_lo[h], BloT, bn, K, k0 + 32 * h, tid);
    }
    __syncthreads();  // vmcnt(0) drained by compiler before barrier

#pragma unroll
    for (int h = 0; h < 2; ++h) {
      f16x8 ah[FRM], al[FRM], bh[FRN], bl[FRN];
#pragma unroll
      for (int m = 0; m < FRM; ++m) {
        const int r = wr * WROWS + m * 16 + lr;
        ah[m] = frag_ld(As_hi[h], r, lk);
        if (ALO) al[m] = frag_ld(As_lo[h], r, lk);
      }
#pragma unroll
      for (int n = 0; n < FRN; ++n) {
        const int r = wc * WCOLS + n * 16 + lr;
        bh[n] = frag_ld(Bs_hi[h], r, lk);
        bl[n] = frag_ld(Bs_lo[h], r, lk);
      }
#pragma unroll
      for (int m = 0; m < FRM; ++m)
#pragma unroll
        for (int n = 0; n < FRN; ++n) {
          acc[m][n] = __builtin_amdgcn_mfma_f32_16x16x32_f16(ah[m], bh[n], acc[m][n], 0, 0, 0);
          acc[m][n] = __builtin_amdgcn_mfma_f32_16x16x32_f16(ah[m], bl[n], acc[m][n], 0, 0, 0);
          if (ALO)
            acc[m][n] = __builtin_amdgcn_mfma_f32_16x16x32_f16(al[m], bh[n], acc[m][n], 0, 0, 0);
        }
    }
  }

  // epilogue
#pragma unroll
  for (int m = 0; m < FRM; ++m)
#pragma unroll
    for (int n = 0; n < FRN; ++n) {
      const int Cc = bn + wc * WCOLS + n * 16 + lr;
      float bv;
      if (EPI == 3) bv = (Cc < 512) ? bias[Cc] : bias2[Cc - 512];
      else          bv = bias[Cc];
#pragma unroll
      for (int q = 0; q < 4; ++q) {
        const int R = bm + wr * WROWS + m * 16 + lk * 4 + q;
        float v = acc[m][n][q] + bv;
        if (EPI == 0) {
          v = fmaxf(v, 0.0f);
          const _Float16 h = (_Float16)v;
          const _Float16 l = (_Float16)(v - (float)h);
          const size_t off = (size_t)R * N + kswz(Cc, R);
          ChiOut[off] = h;
          CloOut[off] = l;
        } else if (EPI == 1) {
          Cf32[(size_t)R * N + Cc] = 1.0f / (1.0f + expf(-v));
        } else if (EPI == 2) {
          Cf32[(size_t)R * N + Cc] = v;
        } else {  // EPI == 3: dual relu split output
          v = fmaxf(v, 0.0f);
          const _Float16 h = (_Float16)v;
          const _Float16 l = (_Float16)(v - (float)h);
          if (Cc < 512) {
            const size_t off = (size_t)R * 512 + kswz(Cc, R);
            ChiOut[off] = h;
            CloOut[off] = l;
          } else {
            const int c2 = Cc - 512;
            const size_t off = (size_t)R * 1024 + kswz(c2, R);
            Chi2[off] = h;
            Clo2[off] = l;
          }
        }
      }
    }
}

// ---------------------------------------------------------------------------
// Round-15: ALL conversions fused into one dispatch (was 7).
// Blocks 0..2047: xconv (x -> swizzled fp16 hi plane).
// Blocks 2048..2887: wconv 64x64 tiles across the 6 weight matrices.
// ---------------------------------------------------------------------------
__global__ __launch_bounds__(256)
void convert_all(const float* __restrict__ x, _Float16* __restrict__ x_hi,
                 const float* __restrict__ sw1, const float* __restrict__ pw1,
                 _Float16* __restrict__ sB_hi, _Float16* __restrict__ sB_lo,
                 const float* __restrict__ sw2,
                 _Float16* __restrict__ sw2T_hi, _Float16* __restrict__ sw2T_lo,
                 const float* __restrict__ pw2,
                 _Float16* __restrict__ pw2T_hi, _Float16* __restrict__ pw2T_lo,
                 const float* __restrict__ pw3,
                 _Float16* __restrict__ pw3T_hi, _Float16* __restrict__ pw3T_lo,
                 const float* __restrict__ pw4,
                 _Float16* __restrict__ pw4T_hi, _Float16* __restrict__ pw4T_lo)
{
  __shared__ float tile[64][65];
  int bid = blockIdx.x;
  const int t = threadIdx.x;

  if (bid < 2048) {
    // ---- xconv: one-hot x (exact in fp16), swizzled hi plane ----
    const int gid = bid * 256 + t;
    const int R = gid >> 6, slot = gid & 63;
    const float4* p = (const float4*)(x + (size_t)R * 512 + slot * 8);
    const float4 a = p[0], b = p[1];
    f16x8 h;
    h[0] = (_Float16)a.x; h[1] = (_Float16)a.y; h[2] = (_Float16)a.z; h[3] = (_Float16)a.w;
    h[4] = (_Float16)b.x; h[5] = (_Float16)b.y; h[6] = (_Float16)b.z; h[7] = (_Float16)b.w;
    const int chunk = (slot >> 2) << 5;
    const int s = (slot & 3) ^ ((R >> 1) & 3);
    *(f16x8*)(x_hi + (size_t)R * 512 + chunk + s * 8) = h;
    return;
  }
  bid -= 2048;

  // ---- wconv tile dispatch (all dims compile-time constants) ----
  const float* w; _Float16* hiT; _Float16* loT; int K, N, tile_id;
  if (bid < 64)        { w = sw1; hiT = sB_hi;                      loT = sB_lo;                      K = 512;  N = 512;  tile_id = bid; }
  else if (bid < 192)  { w = pw1; hiT = sB_hi + (size_t)512 * 512;  loT = sB_lo + (size_t)512 * 512;  K = 512;  N = 1024; tile_id = bid - 64; }
  else if (bid < 200)  { w = sw2; hiT = sw2T_hi;                    loT = sw2T_lo;                    K = 512;  N = 64;   tile_id = bid - 192; }
  else if (bid < 456)  { w = pw2; hiT = pw2T_hi;                    loT = pw2T_lo;                    K = 1024; N = 1024; tile_id = bid - 200; }
  else if (bid < 712)  { w = pw3; hiT = pw3T_hi;                    loT = pw3T_lo;                    K = 1024; N = 1024; tile_id = bid - 456; }
  else                 { w = pw4; hiT = pw4T_hi;                    loT = pw4T_lo;                    K = 1024; N = 512;  tile_id = bid - 712; }

  const int ntx = N / 64;
  const int n0 = (tile_id % ntx) * 64;
  const int k0 = (tile_id / ntx) * 64;
  const int c = t & 63, r4 = t >> 6;
#pragma unroll
  for (int i = 0; i < 16; ++i) {
    const int r = r4 * 16 + i;
    tile[r][c] = w[(size_t)(k0 + r) * N + n0 + c];
  }
  __syncthreads();
#pragma unroll
  for (int i = 0; i < 16; ++i) {
    const int n = r4 * 16 + i;      // n-rel
    const int k = c;                // k-rel
    const float v = tile[k][n];
    const _Float16 h = (_Float16)v;
    const _Float16 l = (_Float16)(v - (float)h);
    const int R = n0 + n;
    const size_t off = (size_t)R * K + kswz(k0 + k, R);
    hiT[off] = h;
    loT[off] = l;
  }
}

// ---------------------------------------------------------------------------
// Finalize (unchanged from the passing round-5 kernel)
// ---------------------------------------------------------------------------
__global__ __launch_bounds__(256)
void finalize_kernel(const float* __restrict__ x,
                     const float* __restrict__ truth,
                     const float* __restrict__ Pm,
                     const float* __restrict__ Wm,
                     float* __restrict__ o_truth,
                     float* __restrict__ o_xcf,
                     uint32_t ka0, uint32_t ka1,
                     uint32_t kb0, uint32_t kb1,
                     uint32_t kg0, uint32_t kg1)
{
  const int gid = blockIdx.x * 256 + threadIdx.x;
  const int b = gid >> 6;
  const int n = gid & 63;
  const size_t ro = (size_t)b * DD + (size_t)n * CC;

  {
    float4 t0 = *reinterpret_cast<const float4*>(truth + ro);
    float4 t1 = *reinterpret_cast<const float4*>(truth + ro + 4);
    *reinterpret_cast<float4*>(o_truth + ro) = t0;
    *reinterpret_cast<float4*>(o_truth + ro + 4) = t1;
  }

  float x8[8];
  {
    float4 a = *reinterpret_cast<const float4*>(x + ro);
    float4 c = *reinterpret_cast<const float4*>(x + ro + 4);
    x8[0] = a.x; x8[1] = a.y; x8[2] = a.z; x8[3] = a.w;
    x8[4] = c.x; x8[5] = c.y; x8[6] = c.z; x8[7] = c.w;
  }
  int curr = 0;
  {
    float xm = x8[0];
#pragma unroll
    for (int c = 1; c < 8; ++c) if (x8[c] > xm) { xm = x8[c]; curr = c; }
  }

  const uint32_t ia = (uint32_t)(b * NN + n);
  const float ua = jax_uniform(tf_bits_p(ka0, ka1, ia));
  const float ub = jax_uniform(tf_bits_p(kb0, kb1, ia));
  const float eaa = expf(-logf(-logf(ua)));
  const float ebb = expf(-logf(-logf(ub)));
  const float Pv = Pm[(size_t)b * NN + n];
  const float no = Pv * eaa / 0.7f;
  const float de = no + (1.0f - Pv) * ebb / 0.7f;
  const float prob = no / de;

  float g8[8];
#pragma unroll
  for (int c = 0; c < 8; ++c)
    g8[c] = -logf(-logf(jax_uniform(tf_bits_p(kg0, kg1, ia * 8u + (uint32_t)c))));

  float w8[8];
  {
    float4 a = *reinterpret_cast<const float4*>(Wm + ro);
    float4 c = *reinterpret_cast<const float4*>(Wm + ro + 4);
    w8[0] = a.x; w8[1] = a.y; w8[2] = a.z; w8[3] = a.w;
    w8[4] = c.x; w8[5] = c.y; w8[6] = c.z; w8[7] = c.w;
  }

  int diff = 0;
  if (n == 2) {
    float mx = w8[0];
#pragma unroll
    for (int c = 1; c < 8; ++c) mx = fmaxf(mx, w8[c]);
    float e[8], s = 0.0f;
#pragma unroll
    for (int c = 0; c < 8; ++c) { e[c] = expf(w8[c] - mx); s += e[c]; }
    float l2[8];
#pragma unroll
    for (int c = 0; c < 8; ++c)
      l2[c] = (logf(0.9f * (e[c] / s) + 0.0125f) + g8[c]) / 0.7f;
    float mx2 = l2[0];
#pragma unroll
    for (int c = 1; c < 8; ++c) mx2 = fmaxf(mx2, l2[c]);
    float e2[8], s2 = 0.0f;
#pragma unroll
    for (int c = 0; c < 8; ++c) { e2[c] = expf(l2[c] - mx2); s2 += e2[c]; }
    float bv = -1e30f; int am = 0;
#pragma unroll
    for (int c = 0; c < 8; ++c) {
      float ov = prob * (e2[c] / s2) + (1.0f - prob) * x8[c];
      if (ov > bv) { bv = ov; am = c; }
    }
    diff = am - curr;
  }
  diff = __shfl(diff, 2, 64);
  const bool cst = (diff == 0);
  const bool inc = (diff > 0);

  float p2 = prob;
  if (n == 7) {
    float pc = prob * (cst ? 0.0f : 1.0f) + (inc ? 1.0f : 0.0f);
    p2 = fminf(fmaxf(pc, 0.0f), 1.0f);
  }

  const bool causal = (n == 0) | (n == 5) | (n == 10);
  float lg[8];
#pragma unroll
  for (int c = 0; c < 8; ++c) {
    float m = 0.0f;
    if (causal) m = (c < curr) ? -100.0f : 1.0f;
    if (n == 7) m = (inc && (c < curr + 1)) ? -100.0f : 1.0f;
    lg[c] = w8[c] + m;
  }

  float mx = lg[0];
#pragma unroll
  for (int c = 1; c < 8; ++c) mx = fmaxf(mx, lg[c]);
  float e[8], s = 0.0f;
#pragma unroll
  for (int c = 0; c < 8; ++c) { e[c] = expf(lg[c] - mx); s += e[c]; }
  float l2[8];
#pragma unroll
  for (int c = 0; c < 8; ++c)
    l2[c] = (logf(0.9f * (e[c] / s) + 0.0125f) + g8[c]) / 0.7f;
  float mx2 = l2[0];
#pragma unroll
  for (int c = 1; c < 8; ++c) mx2 = fmaxf(mx2, l2[c]);
  float e2[8], s2 = 0.0f;
#pragma unroll
  for (int c = 0; c < 8; ++c) { e2[c] = expf(l2[c] - mx2); s2 += e2[c]; }

  float4 o0, o1;
  float* op = &o0.x;
#pragma unroll
  for (int c = 0; c < 4; ++c) op[c] = p2 * (e2[c] / s2) + (1.0f - p2) * x8[c];
  float* op1 = &o1.x;
#pragma unroll
  for (int c = 0; c < 4; ++c) op1[c] = p2 * (e2[c + 4] / s2) + (1.0f - p2) * x8[c + 4];
  *reinterpret_cast<float4*>(o_xcf + ro) = o0;
  *reinterpret_cast<float4*>(o_xcf + ro + 4) = o1;
}

// ---------------------------------------------------------------------------
// Launch
// ---------------------------------------------------------------------------
extern "C" void kernel_launch(void* const* d_in, const int* in_sizes, int n_in,
                              void* d_out, int out_size, void* d_ws, size_t ws_size,
                              hipStream_t stream)
{
  const float* x     = (const float*)d_in[0];
  const float* truth = (const float*)d_in[1];
  const float* sw1   = (const float*)d_in[2];
  const float* sb1   = (const float*)d_in[3];
  const float* sw2   = (const float*)d_in[4];
  const float* sb2   = (const float*)d_in[5];
  const float* pw1   = (const float*)d_in[6];
  const float* pb1   = (const float*)d_in[7];
  const float* pw2   = (const float*)d_in[8];
  const float* pb2   = (const float*)d_in[9];
  const float* pw3   = (const float*)d_in[10];
  const float* pb3   = (const float*)d_in[11];
  const float* pw4   = (const float*)d_in[12];
  const float* pb4   = (const float*)d_in[13];

  float* out      = (float*)d_out;
  float* o_truth  = out;                       // B*D f32
  float* o_xcf    = out + (size_t)BB * DD;     // B*D
  float* o_P      = o_xcf + (size_t)BB * DD;   // B*N
  float* o_W      = o_P + (size_t)BB * NN;     // B*D

  // -------- ws layout --------
  _Float16* wsb = (_Float16*)d_ws;
  size_t cur = 0;
  auto alloc = [&](size_t nelem) { _Float16* p = wsb + cur; cur += nelem; return p; };
  // merged B-plane for G1+G3: rows 0-511 = sw1 cols, rows 512-1535 = pw1 cols
  _Float16* sB_hi  = alloc((size_t)1536 * 512);
  _Float16* sB_lo  = alloc((size_t)1536 * 512);
  _Float16* sw2T_hi = alloc(64 * 512);    _Float16* sw2T_lo = alloc(64 * 512);
  _Float16* pw2T_hi = alloc(1024 * 1024); _Float16* pw2T_lo = alloc(1024 * 1024);
  _Float16* pw3T_hi = alloc(1024 * 1024); _Float16* pw3T_lo = alloc(1024 * 1024);
  _Float16* pw4T_hi = alloc(512 * 1024);  _Float16* pw4T_lo = alloc(512 * 1024);
  // R1: 32MB region. First holds x_hi(8MB)+s1_hi(8MB)+s1_lo(8MB); later h2.
  _Float16* R1 = alloc((size_t)16 * 1024 * 1024);
  _Float16* x_hi  = R1;
  _Float16* s1_hi = R1 + (size_t)BB * HSS;
  _Float16* s1_lo = s1_hi + (size_t)BB * HSS;
  _Float16* h2_hi = R1;
  _Float16* h2_lo = R1 + (size_t)BB * HPP;
  // R2: the truth+xcf region of d_out (32MB), free until finalize.
  _Float16* h1_hi = (_Float16*)d_out;
  _Float16* h1_lo = h1_hi + (size_t)BB * HPP;
  _Float16* h3_hi = h1_hi;
  _Float16* h3_lo = h1_lo;

  // JAX foldlike split (threefry_partitionable), verified round 5.
  uint32_t ka0, ka1, kb0, kb1, kg0, kg1;
  threefry2x32(0u, 42u, 0u, 0u, ka0, ka1);
  threefry2x32(0u, 42u, 0u, 1u, kb0, kb1);
  threefry2x32(0u, 42u, 0u, 2u, kg0, kg1);

  dim3 blk(256);

  // -------- fused conversions (1 dispatch, was 7) --------
  convert_all<<<dim3(2048 + 840), blk, 0, stream>>>(
      x, x_hi,
      sw1, pw1, sB_hi, sB_lo,
      sw2, sw2T_hi, sw2T_lo,
      pw2, pw2T_hi, pw2T_lo,
      pw3, pw3T_hi, pw3T_lo,
      pw4, pw4T_hi, pw4T_lo);

  // -------- GEMM chain --------
  // G1+G3 merged: [s1 | h1] = relu(x @ [sw1|pw1] + [sb1|pb1])  (no A-lo)
  gemm_mfma<128, 128, 0, 3><<<dim3(1536 / 128, BB / 128), blk, 0, stream>>>(
      x_hi, nullptr, sB_hi, sB_lo, sb1, s1_hi, s1_lo, nullptr, BB, 1536, DD,
      pb1, h1_hi, h1_lo);
  // G2: P = sigmoid(s1@sw2+sb2)
  gemm_mfma<128, 64, 1, 1><<<dim3(NN / 64, BB / 128), blk, 0, stream>>>(
      s1_hi, s1_lo, sw2T_hi, sw2T_lo, sb2, nullptr, nullptr, o_P, BB, NN, HSS,
      nullptr, nullptr, nullptr);
  // G4: h2 = relu(h1@pw2+pb2) -> R1 (x,s1 dead)
  gemm_mfma<128, 128, 1, 0><<<dim3(HPP / 128, BB / 128), blk, 0, stream>>>(
      h1_hi, h1_lo, pw2T_hi, pw2T_lo, pb2, h2_hi, h2_lo, nullptr, BB, HPP, HPP,
      nullptr, nullptr, nullptr);
  // G5: h3 = relu(h2@pw3+pb3) -> R2 (over h1)
  gemm_mfma<128, 128, 1, 0><<<dim3(HPP / 128, BB / 128), blk, 0, stream>>>(
      h2_hi, h2_lo, pw3T_hi, pw3T_lo, pb3, h3_hi, h3_lo, nullptr, BB, HPP, HPP,
      nullptr, nullptr, nullptr);
  // G6: W = h3@pw4+pb4 -> o_W (f32)
  gemm_mfma<128, 128, 1, 2><<<dim3(DD / 128, BB / 128), blk, 0, stream>>>(
      h3_hi, h3_lo, pw4T_hi, pw4T_lo, pb4, nullptr, nullptr, o_W, BB, DD, HPP,
      nullptr, nullptr, nullptr);

  // -------- finalize (writes o_truth/o_xcf over R2 after G6 consumed h3) ----
  finalize_kernel<<<dim3(BB * NN / 256), blk, 0, stream>>>(
      x, truth, o_P, o_W, o_truth, o_xcf,
      ka0, ka1, kb0, kb1, kg0, kg1);
}